// Round 1
// baseline (141.858 us; speedup 1.0000x reference)
//
#include <hip/hip_runtime.h>
#include <stdint.h>

// -------------------------------------------------------------------------
// UpperBandEntropyLoss16 via MFMA.
//
// R9 -> R10: timed region is dominated by two harness 384-MiB poison fills
// (117.6 us, untouchable). Controllable part is ~24 us: dct kernel (~16-18,
// HBM-bound at 100.66 MB read) + reduce (~4-6, single-wg latency-bound over
// 98 KB). R10 shrinks the reduction tail: (1) per-wg combine of the 4 wave
// partials through 16 B of LDS -> partials 24576 -> 6144 floats; (2) slim
// 512-thread reduce with 3 unrolled float4 rounds. Main kernel unchanged
// otherwise (R9 structure: truncating bf16 pack, dense band remap).
// -------------------------------------------------------------------------

typedef float f32x4 __attribute__((ext_vector_type(4)));
typedef short bf16x8 __attribute__((ext_vector_type(8)));

constexpr double kPi = 3.14159265358979323846;

constexpr double ccos(double x) {
    while (x > kPi) x -= 2.0 * kPi;
    while (x < -kPi) x += 2.0 * kPi;
    double x2 = x * x;
    double term = 1.0, sum = 1.0;
    for (int k = 1; k <= 24; ++k) {
        term *= -x2 / (double)((2 * k - 1) * (2 * k));
        sum += term;
    }
    return sum;
}

// HARM[i][f] = cos((2i+1) * f*pi/32), f32-rounded like numpy's build.
constexpr float fharm(int i, int f) {
    float colf = (float)((double)f * kPi) / 32.0f;
    float arg = (2.0f * (float)i + 1.0f) * colf;
    return (float)ccos((double)arg);
}

constexpr uint16_t f2bf(float f) {
    unsigned u = __builtin_bit_cast(unsigned, f);
    return (uint16_t)((u + 0x7fffu + ((u >> 16) & 1u)) >> 16);
}

// MFMA 16x16x32 fragment layouts (gfx950, HW-verified in guide):
//   A[m = lane&15][k = (lane>>4)*8 + j]   (8 bf16 / lane)
//   B[k = (lane>>4)*8 + j][n = lane&15]
//   C/D: col = lane&15, row = (lane>>4)*4 + reg
struct FragTables {
    alignas(16) uint32_t blo[64][4];  // B = [G2n ; 0]   (selects K lower half)
    alignas(16) uint32_t bhi[64][4];  // B = [0 ; G2n]   (selects K upper half)
    alignas(16) uint32_t a2[64][4];   // A = [Gu | 0],  Gu[u][i]=H[i][u]*n_u*S
    constexpr FragTables() : blo{}, bhi{}, a2{} {
        for (int l = 0; l < 64; ++l) {
            const int n = l & 15;  // B: freq col v ; A2: freq row u
            const int q = l >> 4;
            uint16_t slo[8] = {}, shi[8] = {}, sa[8] = {};
            for (int s = 0; s < 8; ++s) {
                const int k = 8 * q + s;
                if (k < 16) {
                    float g = fharm(k, n) *
                              ((n == 0) ? 0.70710678118654752440f : 1.0f);
                    slo[s] = f2bf(g);
                    sa[s] = f2bf(g * 0.17677669529663688110f);  // 1/sqrt(32)
                } else {
                    float g = fharm(k - 16, n) *
                              ((n == 0) ? 0.70710678118654752440f : 1.0f);
                    shi[s] = f2bf(g);
                }
            }
            for (int d = 0; d < 4; ++d) {
                blo[l][d] = (uint32_t)slo[2 * d] | ((uint32_t)slo[2 * d + 1] << 16);
                bhi[l][d] = (uint32_t)shi[2 * d] | ((uint32_t)shi[2 * d + 1] << 16);
                a2[l][d] = (uint32_t)sa[2 * d] | ((uint32_t)sa[2 * d + 1] << 16);
            }
        }
    }
};
__constant__ FragTables kF{};

#define NWG 6144
#define NPART NWG  // one combined partial per workgroup (R10)

// Intra-wave phase boundary: HW lockstep + in-order DS pipe give ordering;
// the waitcnt+clobber stops the compiler from reordering across it.
#define WAVE_LDS_FENCE() asm volatile("s_waitcnt lgkmcnt(0)" ::: "memory")

// Truncating bf16x2 pack: low half from a's high 16 bits, high half from b.
// 2 VALU ops (lshr + and_or); truncation error <= 2^-8 rel, fine here.
__device__ __forceinline__ uint32_t pk2(float a, float b) {
    return (__float_as_uint(a) >> 16) | (__float_as_uint(b) & 0xffff0000u);
}

__global__ __launch_bounds__(256, 4) void dct_entropy_kernel(
    const float* __restrict__ x, float* __restrict__ partials) {
    // per-wave region: 1344 dwords (W_cm 768 + Ccm 1296 overlaid, + slack)
    __shared__ float smem[4 * 1344];
    __shared__ float pw[4];  // per-wave entropy partials (R10 wg-combine)

    const int t = threadIdx.x;
    const int wave = t >> 6;
    const int lane = t & 63;
    const int l15 = lane & 15;  // A-row i / D-col v / entropy slot group
    const int q = lane >> 4;
    float* R = smem + wave * 1344;
    uint32_t* Rw = (uint32_t*)R;

    const int g = blockIdx.x;
    const int bc = g >> 8;         // 0..23 (b*c)
    const int br = (g >> 2) & 63;  // block row
    const int cg = g & 3;          // 256-col group
    const float* gbase =
        x + ((size_t)bc << 20) + ((size_t)br << 14) + (cg << 8) + (wave << 6);

    // ---- A-frags: lane reads X[i=l15][32c + 8q + 0..7], c=0,1 ----
    const float* rp = gbase + (size_t)l15 * 1024 + 8 * q;
    float4 lo0 = *(const float4*)(rp);
    float4 hi0 = *(const float4*)(rp + 4);
    float4 lo1 = *(const float4*)(rp + 32);
    float4 hi1 = *(const float4*)(rp + 36);

    const bf16x8 fBlo = __builtin_bit_cast(bf16x8, *(const uint4*)kF.blo[lane]);
    const bf16x8 fBhi = __builtin_bit_cast(bf16x8, *(const uint4*)kF.bhi[lane]);
    const bf16x8 fA2 = __builtin_bit_cast(bf16x8, *(const uint4*)kF.a2[lane]);

    uint4 ua0 = {pk2(lo0.x, lo0.y), pk2(lo0.z, lo0.w),
                 pk2(hi0.x, hi0.y), pk2(hi0.z, hi0.w)};
    uint4 ua1 = {pk2(lo1.x, lo1.y), pk2(lo1.z, lo1.w),
                 pk2(hi1.x, hi1.y), pk2(hi1.z, hi1.w)};
    const bf16x8 fA0 = __builtin_bit_cast(bf16x8, ua0);
    const bf16x8 fA1 = __builtin_bit_cast(bf16x8, ua1);

    // ---- stage A: W_b = X_b * G2n  (4 MFMAs; B const selects K half) ----
    const f32x4 z = {0.0f, 0.0f, 0.0f, 0.0f};
    f32x4 W0 = __builtin_amdgcn_mfma_f32_16x16x32_bf16(fA0, fBlo, z, 0, 0, 0);
    f32x4 W1 = __builtin_amdgcn_mfma_f32_16x16x32_bf16(fA0, fBhi, z, 0, 0, 0);
    f32x4 W2 = __builtin_amdgcn_mfma_f32_16x16x32_bf16(fA1, fBlo, z, 0, 0, 0);
    f32x4 W3 = __builtin_amdgcn_mfma_f32_16x16x32_bf16(fA1, fBhi, z, 0, 0, 0);

    // ---- transpose: D-layout -> B-layout via LDS (b64 writes) ----
    // W_cm[block][v][i] bf16, row pitch 12 dwords; dwords 8..11 slack.
    {
        const int wi = 12 * l15 + 2 * q;
        *(uint2*)(&Rw[wi]) = make_uint2(pk2(W0.x, W0.y), pk2(W0.z, W0.w));
        *(uint2*)(&Rw[192 + wi]) = make_uint2(pk2(W1.x, W1.y), pk2(W1.z, W1.w));
        *(uint2*)(&Rw[384 + wi]) = make_uint2(pk2(W2.x, W2.y), pk2(W2.z, W2.w));
        *(uint2*)(&Rw[576 + wi]) = make_uint2(pk2(W3.x, W3.y), pk2(W3.z, W3.w));
    }
    WAVE_LDS_FENCE();

    // B-frag read; k>=16 lanes re-read k<16 data (annihilated by fA2's
    // exact zero padding; avoids 0*NaN from unwritten slack — R6 fix).
    bf16x8 fW[4];
    {
        const int ri = 12 * l15 + 4 * (q & 1);
#pragma unroll
        for (int b = 0; b < 4; ++b)
            fW[b] = __builtin_bit_cast(bf16x8, *(const uint4*)(&Rw[192 * b + ri]));
    }
    WAVE_LDS_FENCE();  // all B reads ordered before Ccm overlay-writes

    // ---- stage B: C_b = Gu * W_b; store column-major fp32 ----
    // Ccm[block][v][u] pitch 20 dwords, block base 324 dwords.
    {
#pragma unroll
        for (int b = 0; b < 4; ++b) {
            f32x4 C = __builtin_amdgcn_mfma_f32_16x16x32_bf16(fA2, fW[b], z, 0, 0, 0);
            *(f32x4*)(&R[324 * b + 20 * l15 + 4 * q]) = C;
        }
    }
    WAVE_LDS_FENCE();

    // ---- entropy: dense band remap, 8 in-band coeffs per lane ----
    // Pair p = l15>>1 couples column v1=p (u_min=15-p, count p+1) with
    // column v2=15-p (u_min=p+1, count 15-p): exactly 16 slots. Half h
    // = l15&1 takes slots s=8h..8h+7. Address (dwords into block region):
    //   s <= p : 19p + 15 + s       (run in column p)
    //   else   : 300 - 20p + s      (run in column 15-p)
    {
        const int p = l15 >> 1;
        const int h = l15 & 1;
        const float* Cb = &R[324 * q];
        float c[8];
#pragma unroll
        for (int j = 0; j < 8; ++j) {
            const int s = 8 * h + j;
            const int off = (s <= p) ? (19 * p + 15 + s) : (300 - 20 * p + s);
            c[j] = Cb[off];
        }

        float s = ((c[0] + c[1]) + (c[2] + c[3])) +
                  ((c[4] + c[5]) + (c[6] + c[7]));
#pragma unroll
        for (int m = 1; m <= 8; m <<= 1) s += __shfl_xor(s, m);
        const float mean = s * (1.0f / 128.0f);

        float a[8];
        float sq = 0.0f;
#pragma unroll
        for (int j = 0; j < 8; ++j) {
            a[j] = (c[j] < mean) ? 1e-12f : (fabsf(c[j]) + 1e-12f);
            sq = fmaf(a[j], a[j], sq);
        }
#pragma unroll
        for (int m = 1; m <= 8; m <<= 1) sq += __shfl_xor(sq, m);
        const float inv = 1.0f / fmaxf(sqrtf(sq), 1e-12f);

        float e = 0.0f;
#pragma unroll
        for (int j = 0; j < 8; ++j) {
            float pj = a[j] * inv;
            e = fmaf(pj, __log2f(pj), e);
        }
        // reduce within block (xor 1..8), then across the wave's 4 blocks
#pragma unroll
        for (int m = 1; m <= 32; m <<= 1) e += __shfl_xor(e, m);
        if (lane == 0) pw[wave] = e;
    }

    // ---- R10: combine the 4 wave partials -> one float per wg ----
    __syncthreads();
    if (t == 0) partials[g] = (pw[0] + pw[1]) + (pw[2] + pw[3]);
}

__global__ __launch_bounds__(512) void reduce_partials(
    const float* __restrict__ partials, float* __restrict__ out) {
    __shared__ float s[8];
    // 6144 floats = 1536 float4; 512 threads x 3 unrolled rounds.
    const float4* p4 = (const float4*)partials;
    float v = 0.0f;
#pragma unroll
    for (int i = 0; i < 3; ++i) {
        float4 f = p4[threadIdx.x + 512 * i];
        v += (f.x + f.y) + (f.z + f.w);
    }
#pragma unroll
    for (int m = 1; m <= 32; m <<= 1) v += __shfl_xor(v, m);
    if ((threadIdx.x & 63) == 0) s[threadIdx.x >> 6] = v;
    __syncthreads();
    if (threadIdx.x < 8) {
        float tot = s[threadIdx.x];
#pragma unroll
        for (int m = 1; m <= 4; m <<= 1) tot += __shfl_xor(tot, m);
        if (threadIdx.x == 0) out[0] = tot * (-1.0f / 98304.0f);
    }
}

extern "C" void kernel_launch(void* const* d_in, const int* in_sizes, int n_in,
                              void* d_out, int out_size, void* d_ws,
                              size_t ws_size, hipStream_t stream) {
    const float* x = (const float*)d_in[0];
    float* out = (float*)d_out;
    float* ws = (float*)d_ws;  // 6144 per-wg partials
    dct_entropy_kernel<<<NWG, 256, 0, stream>>>(x, ws);
    reduce_partials<<<1, 512, 0, stream>>>(ws, out);
}